// Round 1
// baseline (608.812 us; speedup 1.0000x reference)
//
#include <hip/hip_runtime.h>

// Interactions: GCN-style 2-conv network.
// out = relu(x@W0 + b0); for i in 0..1: h = out@Wc[i]; agg = scatter_add(norm*h[src], dst);
//   out += relu(agg + bc[i])
// norm = dinv[src]*w*dinv[dst], dinv = rsqrt(scatter_add(w, dst)) (0 where deg==0)

#define TPB 256

__global__ void deg_kernel(const float* __restrict__ w, const int* __restrict__ dst,
                           float* __restrict__ deg, int E) {
    int e = blockIdx.x * TPB + threadIdx.x;
    if (e < E) atomicAdd(&deg[dst[e]], w[e]);
}

__global__ void norm_kernel(const float* __restrict__ w, const int* __restrict__ src,
                            const int* __restrict__ dst, const float* __restrict__ deg,
                            float* __restrict__ norm, int E) {
    int e = blockIdx.x * TPB + threadIdx.x;
    if (e >= E) return;
    float ds = deg[src[e]], dt = deg[dst[e]];
    float is = ds > 0.f ? rsqrtf(ds) : 0.f;
    float it = dt > 0.f ? rsqrtf(dt) : 0.f;
    norm[e] = is * w[e] * it;
}

// C[n,j] = (relu?)(sum_k A[n,k]*W[k,j] (+ bias[j]))  for D=64. 4 nodes / 256-thread block.
template <bool RELU, bool BIAS>
__global__ void gemm64(const float* __restrict__ A, const float* __restrict__ W,
                       const float* __restrict__ bias, float* __restrict__ C, int n) {
    __shared__ float sW[64][64];   // 16 KB
    __shared__ float sA[4][64];
    int t = threadIdx.x;
    const float4* W4 = (const float4*)W;
    float4* sW4 = (float4*)(&sW[0][0]);
#pragma unroll
    for (int i = 0; i < 4; ++i) sW4[t + i * 256] = W4[t + i * 256];
    int node = blockIdx.x * 4 + (t >> 6);
    int j = t & 63;
    if (node < n) sA[t >> 6][j] = A[(size_t)node * 64 + j];
    __syncthreads();
    if (node >= n) return;
    float acc = BIAS ? bias[j] : 0.f;
    const float* a = sA[t >> 6];
#pragma unroll
    for (int k = 0; k < 64; ++k) acc = fmaf(a[k], sW[k][j], acc);
    C[(size_t)node * 64 + j] = RELU ? fmaxf(acc, 0.f) : acc;
}

// one wave (64 lanes) per edge: lane d handles channel d
__global__ void scatter64(const float* __restrict__ h, const float* __restrict__ norm,
                          const int* __restrict__ src, const int* __restrict__ dst,
                          float* __restrict__ agg, int E) {
    int idx = blockIdx.x * TPB + threadIdx.x;   // E*64 = 64M, fits int32
    int e = idx >> 6;
    if (e >= E) return;
    int d = idx & 63;
    int s = src[e], tn = dst[e];
    atomicAdd(&agg[(size_t)tn * 64 + d], norm[e] * h[(size_t)s * 64 + d]);
}

__global__ void update64(float* __restrict__ out, const float* __restrict__ agg,
                         const float* __restrict__ b, int total) {
    int idx = blockIdx.x * TPB + threadIdx.x;
    if (idx >= total) return;
    int j = idx & 63;
    out[idx] = out[idx] + fmaxf(agg[idx] + b[j], 0.f);
}

extern "C" void kernel_launch(void* const* d_in, const int* in_sizes, int n_in,
                              void* d_out, int out_size, void* d_ws, size_t ws_size,
                              hipStream_t stream) {
    const float* x      = (const float*)d_in[0];
    const int*   ei     = (const int*)d_in[1];
    const float* ew     = (const float*)d_in[2];
    // d_in[3] = edge_attr, unused by the math
    const float* lin0_w = (const float*)d_in[4];
    const float* lin0_b = (const float*)d_in[5];
    const float* conv_w = (const float*)d_in[6];
    const float* conv_b = (const float*)d_in[7];

    const int N = in_sizes[0] / 64;
    const int E = in_sizes[2];
    const int* src = ei;
    const int* dst = ei + E;

    char* ws = (char*)d_ws;
    size_t off = 0;
    float* deg = (float*)(ws + off);
    off += ((size_t)N * 4 + 255) & ~(size_t)255;
    float* norm = (float*)(ws + off);
    off += ((size_t)E * 4 + 255) & ~(size_t)255;
    float* h = (float*)(ws + off);
    off += ((size_t)N * 64 * 4 + 255) & ~(size_t)255;
    float* agg = (float*)(ws + off);

    float* out = (float*)d_out;

    // degree + norm
    hipMemsetAsync(deg, 0, (size_t)N * 4, stream);
    deg_kernel<<<(E + TPB - 1) / TPB, TPB, 0, stream>>>(ew, dst, deg, E);
    norm_kernel<<<(E + TPB - 1) / TPB, TPB, 0, stream>>>(ew, src, dst, deg, norm, E);

    // lin0 + relu
    gemm64<true, true><<<(N + 3) / 4, TPB, 0, stream>>>(x, lin0_w, lin0_b, out, N);

    for (int i = 0; i < 2; ++i) {
        gemm64<false, false><<<(N + 3) / 4, TPB, 0, stream>>>(out, conv_w + (size_t)i * 64 * 64,
                                                              nullptr, h, N);
        hipMemsetAsync(agg, 0, (size_t)N * 64 * 4, stream);
        int total_ec = E * 64;   // 64M
        scatter64<<<(total_ec + TPB - 1) / TPB, TPB, 0, stream>>>(h, norm, src, dst, agg, E);
        update64<<<(N * 64 + TPB - 1) / TPB, TPB, 0, stream>>>(out, agg, conv_b + (size_t)i * 64,
                                                               N * 64);
    }
}

// Round 2
// 450.334 us; speedup vs baseline: 1.3519x; 1.3519x over previous
//
#include <hip/hip_runtime.h>

// GCN-style 2-conv: out = relu(x@W0+b0); 2x { h = out@Wc; out += relu(gather_agg(h) + bc) }
// This round: scatter->gather via in-kernel CSR (by dst). No atomics on the hot path.

#define TPB 256

// count edges per dst + weighted degree, fused
__global__ void count_deg(const float* __restrict__ w, const int* __restrict__ dst,
                          int* __restrict__ cnt, float* __restrict__ deg, int E) {
    int e = blockIdx.x * TPB + threadIdx.x;
    if (e >= E) return;
    int d = dst[e];
    atomicAdd(&cnt[d], 1);
    atomicAdd(&deg[d], w[e]);
}

// single-block exclusive scan of cnt[0..N) -> rowptr[0..N]
__global__ void scan_kernel(const int* __restrict__ cnt, int* __restrict__ rowptr, int N) {
    __shared__ int buf[1024];
    __shared__ int carry;
    int t = threadIdx.x;
    if (t == 0) carry = 0;
    __syncthreads();
    for (int base = 0; base < N; base += 1024) {
        int v = (base + t < N) ? cnt[base + t] : 0;
        buf[t] = v;
        __syncthreads();
#pragma unroll
        for (int offs = 1; offs < 1024; offs <<= 1) {
            int add = (t >= offs) ? buf[t - offs] : 0;
            __syncthreads();
            buf[t] += add;
            __syncthreads();
        }
        if (base + t < N) rowptr[base + t + 1] = carry + buf[t];
        __syncthreads();
        if (t == 0) carry += buf[1023];
        __syncthreads();
    }
    if (t == 0) rowptr[0] = 0;
}

// scatter edges into CSR slots; compute norm = dinv[src]*w*dinv[dst] inline
__global__ void fill_csr(const int* __restrict__ src, const int* __restrict__ dst,
                         const float* __restrict__ w, const float* __restrict__ deg,
                         const int* __restrict__ rowptr, int* __restrict__ cnt2,
                         int* __restrict__ es, float* __restrict__ en, int E) {
    int e = blockIdx.x * TPB + threadIdx.x;
    if (e >= E) return;
    int s = src[e], d = dst[e];
    float ds = deg[s], dt = deg[d];
    float is = ds > 0.f ? rsqrtf(ds) : 0.f;
    float it = dt > 0.f ? rsqrtf(dt) : 0.f;
    float nm = is * w[e] * it;
    int pos = rowptr[d] + atomicAdd(&cnt2[d], 1);
    es[pos] = s;
    en[pos] = nm;
}

// C[n,j] = (relu?)(sum_k A[n,k]*W[k,j] (+ bias[j])) for D=64. 4 nodes / 256-thread block.
template <bool RELU, bool BIAS>
__global__ void gemm64(const float* __restrict__ A, const float* __restrict__ W,
                       const float* __restrict__ bias, float* __restrict__ C, int n) {
    __shared__ float sW[64][64];
    __shared__ float sA[4][64];
    int t = threadIdx.x;
    const float4* W4 = (const float4*)W;
    float4* sW4 = (float4*)(&sW[0][0]);
#pragma unroll
    for (int i = 0; i < 4; ++i) sW4[t + i * 256] = W4[t + i * 256];
    int node = blockIdx.x * 4 + (t >> 6);
    int j = t & 63;
    if (node < n) sA[t >> 6][j] = A[(size_t)node * 64 + j];
    __syncthreads();
    if (node >= n) return;
    float acc = BIAS ? bias[j] : 0.f;
    const float* a = sA[t >> 6];
#pragma unroll
    for (int k = 0; k < 64; ++k) acc = fmaf(a[k], sW[k][j], acc);
    C[(size_t)node * 64 + j] = RELU ? fmaxf(acc, 0.f) : acc;
}

// one wave per dst node: lane = channel. Gathers h[src] rows, accumulates in-register,
// fused residual + bias + relu into out.
__global__ void gather_conv(const float* __restrict__ h, const int* __restrict__ rowptr,
                            const int* __restrict__ es, const float* __restrict__ en,
                            const float* __restrict__ b, float* __restrict__ out, int n) {
    int wid = (blockIdx.x * TPB + threadIdx.x) >> 6;
    int lane = threadIdx.x & 63;
    if (wid >= n) return;
    int beg = rowptr[wid], end = rowptr[wid + 1];
    float acc = 0.f;
    for (int k = beg; k < end; k += 64) {
        int kk = k + lane;
        int sv = (kk < end) ? es[kk] : 0;
        float nv = (kk < end) ? en[kk] : 0.f;
        int c = min(64, end - k);
        for (int j = 0; j < c; ++j) {
            int s = __shfl(sv, j);
            float nm = __shfl(nv, j);
            acc = fmaf(nm, h[(size_t)s * 64 + lane], acc);
        }
    }
    size_t o = (size_t)wid * 64 + lane;
    out[o] = out[o] + fmaxf(acc + b[lane], 0.f);
}

extern "C" void kernel_launch(void* const* d_in, const int* in_sizes, int n_in,
                              void* d_out, int out_size, void* d_ws, size_t ws_size,
                              hipStream_t stream) {
    const float* x      = (const float*)d_in[0];
    const int*   ei     = (const int*)d_in[1];
    const float* ew     = (const float*)d_in[2];
    // d_in[3] = edge_attr, unused
    const float* lin0_w = (const float*)d_in[4];
    const float* lin0_b = (const float*)d_in[5];
    const float* conv_w = (const float*)d_in[6];
    const float* conv_b = (const float*)d_in[7];

    const int N = in_sizes[0] / 64;
    const int E = in_sizes[2];
    const int* src = ei;
    const int* dst = ei + E;

    char* ws = (char*)d_ws;
    size_t off = 0;
    auto alloc = [&](size_t bytes) {
        void* p = ws + off;
        off += (bytes + 255) & ~(size_t)255;
        return p;
    };
    float* deg    = (float*)alloc((size_t)N * 4);
    int*   cnt    = (int*)alloc((size_t)N * 4);
    int*   cnt2   = (int*)alloc((size_t)N * 4);
    int*   rowptr = (int*)alloc(((size_t)N + 1) * 4);
    int*   es     = (int*)alloc((size_t)E * 4);
    float* en     = (float*)alloc((size_t)E * 4);
    float* h      = (float*)alloc((size_t)N * 64 * 4);

    float* out = (float*)d_out;
    int eb = (E + TPB - 1) / TPB;
    int nb_nodes = (N * 64 + TPB - 1) / TPB;   // waves: one per node, 4 nodes/block

    // CSR build
    hipMemsetAsync(deg, 0, (size_t)N * 4, stream);
    hipMemsetAsync(cnt, 0, (size_t)N * 4, stream);
    hipMemsetAsync(cnt2, 0, (size_t)N * 4, stream);
    count_deg<<<eb, TPB, 0, stream>>>(ew, dst, cnt, deg, E);
    scan_kernel<<<1, 1024, 0, stream>>>(cnt, rowptr, N);
    fill_csr<<<eb, TPB, 0, stream>>>(src, dst, ew, deg, rowptr, cnt2, es, en, E);

    // lin0 + relu
    gemm64<true, true><<<(N + 3) / 4, TPB, 0, stream>>>(x, lin0_w, lin0_b, out, N);

    for (int i = 0; i < 2; ++i) {
        gemm64<false, false><<<(N + 3) / 4, TPB, 0, stream>>>(out, conv_w + (size_t)i * 64 * 64,
                                                              nullptr, h, N);
        gather_conv<<<nb_nodes, TPB, 0, stream>>>(h, rowptr, es, en,
                                                  conv_b + (size_t)i * 64, out, N);
    }
}

// Round 3
// 376.261 us; speedup vs baseline: 1.6181x; 1.1969x over previous
//
#include <hip/hip_runtime.h>

// GCN-style 2-conv. This round: CSR build with a single 1M-atomic pass
// (position-returning count), atomic-free fill, degree from CSR row sums.

#define TPB 256

// pos[e] = slot of edge e within its dst row; cnt[d] = edges with dst==d
__global__ void count_pos(const int* __restrict__ dst, int* __restrict__ cnt,
                          int* __restrict__ pos, int E) {
    int e = blockIdx.x * TPB + threadIdx.x;
    if (e < E) pos[e] = atomicAdd(&cnt[dst[e]], 1);
}

// single-block exclusive scan: 1024 threads, chunk-serial + shfl wave scan
__global__ void scan_kernel(const int* __restrict__ cnt, int* __restrict__ rowptr, int N) {
    __shared__ int wpart[16];
    int t = threadIdx.x;
    int chunk = (N + 1023) >> 10;
    int beg = t * chunk;
    int end = min(beg + chunk, N);
    int s = 0;
    for (int i = beg; i < end; ++i) s += cnt[i];
    int lane = t & 63, wid = t >> 6;
    int v = s;
#pragma unroll
    for (int o = 1; o < 64; o <<= 1) {
        int u = __shfl_up(v, o);
        if (lane >= o) v += u;
    }
    if (lane == 63) wpart[wid] = v;
    __syncthreads();
    if (t == 0) {
        int run = 0;
#pragma unroll
        for (int i = 0; i < 16; ++i) { int x = wpart[i]; wpart[i] = run; run += x; }
    }
    __syncthreads();
    int run = wpart[wid] + (v - s);   // exclusive prefix for this thread's chunk
    for (int i = beg; i < end; ++i) { rowptr[i] = run; run += cnt[i]; }
    if (end >= N) rowptr[N] = run;    // every such thread writes the same total
}

// atomic-free CSR fill: es = src in row order, ew2 = w in row order
__global__ void fill2(const int* __restrict__ src, const int* __restrict__ dst,
                      const float* __restrict__ w, const int* __restrict__ rowptr,
                      const int* __restrict__ pos, int* __restrict__ es,
                      float* __restrict__ ew2, int E) {
    int e = blockIdx.x * TPB + threadIdx.x;
    if (e >= E) return;
    int p = rowptr[dst[e]] + pos[e];
    es[p] = src[e];
    ew2[p] = w[e];
}

// dinv[n] = rsqrt(sum of ew2 over row n) or 0
__global__ void dinv_kernel(const int* __restrict__ rowptr, const float* __restrict__ ew2,
                            float* __restrict__ dinv, int N) {
    int n = blockIdx.x * TPB + threadIdx.x;
    if (n >= N) return;
    int b = rowptr[n], e = rowptr[n + 1];
    float s = 0.f;
    for (int k = b; k < e; ++k) s += ew2[k];
    dinv[n] = s > 0.f ? rsqrtf(s) : 0.f;
}

// en[k] = dinv[es[k]] * ew2[k] * dinv[row]; wave per row
__global__ void en_kernel(const int* __restrict__ rowptr, const int* __restrict__ es,
                          const float* __restrict__ ew2, const float* __restrict__ dinv,
                          float* __restrict__ en, int N) {
    int wid = (blockIdx.x * TPB + threadIdx.x) >> 6;
    int lane = threadIdx.x & 63;
    if (wid >= N) return;
    float dd = dinv[wid];
    int b = rowptr[wid], e = rowptr[wid + 1];
    for (int k = b + lane; k < e; k += 64)
        en[k] = dinv[es[k]] * ew2[k] * dd;
}

// C[n,j] = (relu?)(sum_k A[n,k]*W[k,j] (+ bias[j])) for D=64. 4 nodes / block.
template <bool RELU, bool BIAS>
__global__ void gemm64(const float* __restrict__ A, const float* __restrict__ W,
                       const float* __restrict__ bias, float* __restrict__ C, int n) {
    __shared__ float sW[64][64];
    __shared__ float sA[4][64];
    int t = threadIdx.x;
    const float4* W4 = (const float4*)W;
    float4* sW4 = (float4*)(&sW[0][0]);
#pragma unroll
    for (int i = 0; i < 4; ++i) sW4[t + i * 256] = W4[t + i * 256];
    int node = blockIdx.x * 4 + (t >> 6);
    int j = t & 63;
    if (node < n) sA[t >> 6][j] = A[(size_t)node * 64 + j];
    __syncthreads();
    if (node >= n) return;
    float acc = BIAS ? bias[j] : 0.f;
    const float* a = sA[t >> 6];
#pragma unroll
    for (int k = 0; k < 64; ++k) acc = fmaf(a[k], sW[k][j], acc);
    C[(size_t)node * 64 + j] = RELU ? fmaxf(acc, 0.f) : acc;
}

// one wave per dst node: lane = channel; fused residual + bias + relu
__global__ void gather_conv(const float* __restrict__ h, const int* __restrict__ rowptr,
                            const int* __restrict__ es, const float* __restrict__ en,
                            const float* __restrict__ b, float* __restrict__ out, int n) {
    int wid = (blockIdx.x * TPB + threadIdx.x) >> 6;
    int lane = threadIdx.x & 63;
    if (wid >= n) return;
    int beg = rowptr[wid], end = rowptr[wid + 1];
    float acc = 0.f;
    for (int k = beg; k < end; k += 64) {
        int kk = k + lane;
        int sv = (kk < end) ? es[kk] : 0;
        float nv = (kk < end) ? en[kk] : 0.f;
        int c = min(64, end - k);
        for (int j = 0; j < c; ++j) {
            int s = __shfl(sv, j);
            float nm = __shfl(nv, j);
            acc = fmaf(nm, h[(size_t)s * 64 + lane], acc);
        }
    }
    size_t o = (size_t)wid * 64 + lane;
    out[o] = out[o] + fmaxf(acc + b[lane], 0.f);
}

extern "C" void kernel_launch(void* const* d_in, const int* in_sizes, int n_in,
                              void* d_out, int out_size, void* d_ws, size_t ws_size,
                              hipStream_t stream) {
    const float* x      = (const float*)d_in[0];
    const int*   ei     = (const int*)d_in[1];
    const float* ew     = (const float*)d_in[2];
    // d_in[3] = edge_attr, unused
    const float* lin0_w = (const float*)d_in[4];
    const float* lin0_b = (const float*)d_in[5];
    const float* conv_w = (const float*)d_in[6];
    const float* conv_b = (const float*)d_in[7];

    const int N = in_sizes[0] / 64;
    const int E = in_sizes[2];
    const int* src = ei;
    const int* dst = ei + E;

    char* ws = (char*)d_ws;
    size_t off = 0;
    auto alloc = [&](size_t bytes) {
        void* p = ws + off;
        off += (bytes + 255) & ~(size_t)255;
        return p;
    };
    int*   cnt    = (int*)alloc((size_t)N * 4);
    int*   rowptr = (int*)alloc(((size_t)N + 1) * 4);
    float* dinv   = (float*)alloc((size_t)N * 4);
    int*   pos    = (int*)alloc((size_t)E * 4);
    int*   es     = (int*)alloc((size_t)E * 4);
    float* ew2    = (float*)alloc((size_t)E * 4);
    float* en     = (float*)alloc((size_t)E * 4);
    float* h      = (float*)alloc((size_t)N * 64 * 4);

    float* out = (float*)d_out;
    int eb = (E + TPB - 1) / TPB;
    int nb_waves = (N * 64 + TPB - 1) / TPB;     // one wave per node
    int nb_thr   = (N + TPB - 1) / TPB;          // one thread per node

    // CSR build: 1M atomics total
    hipMemsetAsync(cnt, 0, (size_t)N * 4, stream);
    count_pos<<<eb, TPB, 0, stream>>>(dst, cnt, pos, E);
    scan_kernel<<<1, 1024, 0, stream>>>(cnt, rowptr, N);
    fill2<<<eb, TPB, 0, stream>>>(src, dst, ew, rowptr, pos, es, ew2, E);
    dinv_kernel<<<nb_thr, TPB, 0, stream>>>(rowptr, ew2, dinv, N);
    en_kernel<<<nb_waves, TPB, 0, stream>>>(rowptr, es, ew2, dinv, en, N);

    // lin0 + relu
    gemm64<true, true><<<(N + 3) / 4, TPB, 0, stream>>>(x, lin0_w, lin0_b, out, N);

    for (int i = 0; i < 2; ++i) {
        gemm64<false, false><<<(N + 3) / 4, TPB, 0, stream>>>(out, conv_w + (size_t)i * 64 * 64,
                                                              nullptr, h, N);
        gather_conv<<<nb_waves, TPB, 0, stream>>>(h, rowptr, es, en,
                                                  conv_b + (size_t)i * 64, out, N);
    }
}

// Round 4
// 375.016 us; speedup vs baseline: 1.6234x; 1.0033x over previous
//
#include <hip/hip_runtime.h>

// GCN-style 2-conv. This round: CSR build with a single 1M-atomic pass
// (position-returning count), atomic-free fill, degree from CSR row sums.

#define TPB 256

// pos[e] = slot of edge e within its dst row; cnt[d] = edges with dst==d
__global__ void count_pos(const int* __restrict__ dst, int* __restrict__ cnt,
                          int* __restrict__ pos, int E) {
    int e = blockIdx.x * TPB + threadIdx.x;
    if (e < E) pos[e] = atomicAdd(&cnt[dst[e]], 1);
}

// single-block exclusive scan: 1024 threads, chunk-serial + shfl wave scan
__global__ void scan_kernel(const int* __restrict__ cnt, int* __restrict__ rowptr, int N) {
    __shared__ int wpart[16];
    int t = threadIdx.x;
    int chunk = (N + 1023) >> 10;
    int beg = t * chunk;
    int end = min(beg + chunk, N);
    int s = 0;
    for (int i = beg; i < end; ++i) s += cnt[i];
    int lane = t & 63, wid = t >> 6;
    int v = s;
#pragma unroll
    for (int o = 1; o < 64; o <<= 1) {
        int u = __shfl_up(v, o);
        if (lane >= o) v += u;
    }
    if (lane == 63) wpart[wid] = v;
    __syncthreads();
    if (t == 0) {
        int run = 0;
#pragma unroll
        for (int i = 0; i < 16; ++i) { int x = wpart[i]; wpart[i] = run; run += x; }
    }
    __syncthreads();
    int run = wpart[wid] + (v - s);   // exclusive prefix for this thread's chunk
    for (int i = beg; i < end; ++i) { rowptr[i] = run; run += cnt[i]; }
    if (end >= N) rowptr[N] = run;    // every such thread writes the same total
}

// atomic-free CSR fill: es = src in row order, ew2 = w in row order
__global__ void fill2(const int* __restrict__ src, const int* __restrict__ dst,
                      const float* __restrict__ w, const int* __restrict__ rowptr,
                      const int* __restrict__ pos, int* __restrict__ es,
                      float* __restrict__ ew2, int E) {
    int e = blockIdx.x * TPB + threadIdx.x;
    if (e >= E) return;
    int p = rowptr[dst[e]] + pos[e];
    es[p] = src[e];
    ew2[p] = w[e];
}

// dinv[n] = rsqrt(sum of ew2 over row n) or 0
__global__ void dinv_kernel(const int* __restrict__ rowptr, const float* __restrict__ ew2,
                            float* __restrict__ dinv, int N) {
    int n = blockIdx.x * TPB + threadIdx.x;
    if (n >= N) return;
    int b = rowptr[n], e = rowptr[n + 1];
    float s = 0.f;
    for (int k = b; k < e; ++k) s += ew2[k];
    dinv[n] = s > 0.f ? rsqrtf(s) : 0.f;
}

// en[k] = dinv[es[k]] * ew2[k] * dinv[row]; wave per row
__global__ void en_kernel(const int* __restrict__ rowptr, const int* __restrict__ es,
                          const float* __restrict__ ew2, const float* __restrict__ dinv,
                          float* __restrict__ en, int N) {
    int wid = (blockIdx.x * TPB + threadIdx.x) >> 6;
    int lane = threadIdx.x & 63;
    if (wid >= N) return;
    float dd = dinv[wid];
    int b = rowptr[wid], e = rowptr[wid + 1];
    for (int k = b + lane; k < e; k += 64)
        en[k] = dinv[es[k]] * ew2[k] * dd;
}

// C[n,j] = (relu?)(sum_k A[n,k]*W[k,j] (+ bias[j])) for D=64. 4 nodes / block.
template <bool RELU, bool BIAS>
__global__ void gemm64(const float* __restrict__ A, const float* __restrict__ W,
                       const float* __restrict__ bias, float* __restrict__ C, int n) {
    __shared__ float sW[64][64];
    __shared__ float sA[4][64];
    int t = threadIdx.x;
    const float4* W4 = (const float4*)W;
    float4* sW4 = (float4*)(&sW[0][0]);
#pragma unroll
    for (int i = 0; i < 4; ++i) sW4[t + i * 256] = W4[t + i * 256];
    int node = blockIdx.x * 4 + (t >> 6);
    int j = t & 63;
    if (node < n) sA[t >> 6][j] = A[(size_t)node * 64 + j];
    __syncthreads();
    if (node >= n) return;
    float acc = BIAS ? bias[j] : 0.f;
    const float* a = sA[t >> 6];
#pragma unroll
    for (int k = 0; k < 64; ++k) acc = fmaf(a[k], sW[k][j], acc);
    C[(size_t)node * 64 + j] = RELU ? fmaxf(acc, 0.f) : acc;
}

// one wave per dst node: lane = channel; fused residual + bias + relu
__global__ void gather_conv(const float* __restrict__ h, const int* __restrict__ rowptr,
                            const int* __restrict__ es, const float* __restrict__ en,
                            const float* __restrict__ b, float* __restrict__ out, int n) {
    int wid = (blockIdx.x * TPB + threadIdx.x) >> 6;
    int lane = threadIdx.x & 63;
    if (wid >= n) return;
    int beg = rowptr[wid], end = rowptr[wid + 1];
    float acc = 0.f;
    for (int k = beg; k < end; k += 64) {
        int kk = k + lane;
        int sv = (kk < end) ? es[kk] : 0;
        float nv = (kk < end) ? en[kk] : 0.f;
        int c = min(64, end - k);
        for (int j = 0; j < c; ++j) {
            int s = __shfl(sv, j);
            float nm = __shfl(nv, j);
            acc = fmaf(nm, h[(size_t)s * 64 + lane], acc);
        }
    }
    size_t o = (size_t)wid * 64 + lane;
    out[o] = out[o] + fmaxf(acc + b[lane], 0.f);
}

extern "C" void kernel_launch(void* const* d_in, const int* in_sizes, int n_in,
                              void* d_out, int out_size, void* d_ws, size_t ws_size,
                              hipStream_t stream) {
    const float* x      = (const float*)d_in[0];
    const int*   ei     = (const int*)d_in[1];
    const float* ew     = (const float*)d_in[2];
    // d_in[3] = edge_attr, unused
    const float* lin0_w = (const float*)d_in[4];
    const float* lin0_b = (const float*)d_in[5];
    const float* conv_w = (const float*)d_in[6];
    const float* conv_b = (const float*)d_in[7];

    const int N = in_sizes[0] / 64;
    const int E = in_sizes[2];
    const int* src = ei;
    const int* dst = ei + E;

    char* ws = (char*)d_ws;
    size_t off = 0;
    auto alloc = [&](size_t bytes) {
        void* p = ws + off;
        off += (bytes + 255) & ~(size_t)255;
        return p;
    };
    int*   cnt    = (int*)alloc((size_t)N * 4);
    int*   rowptr = (int*)alloc(((size_t)N + 1) * 4);
    float* dinv   = (float*)alloc((size_t)N * 4);
    int*   pos    = (int*)alloc((size_t)E * 4);
    int*   es     = (int*)alloc((size_t)E * 4);
    float* ew2    = (float*)alloc((size_t)E * 4);
    float* en     = (float*)alloc((size_t)E * 4);
    float* h      = (float*)alloc((size_t)N * 64 * 4);

    float* out = (float*)d_out;
    int eb = (E + TPB - 1) / TPB;
    int nb_waves = (N * 64 + TPB - 1) / TPB;     // one wave per node
    int nb_thr   = (N + TPB - 1) / TPB;          // one thread per node

    // CSR build: 1M atomics total
    hipMemsetAsync(cnt, 0, (size_t)N * 4, stream);
    count_pos<<<eb, TPB, 0, stream>>>(dst, cnt, pos, E);
    scan_kernel<<<1, 1024, 0, stream>>>(cnt, rowptr, N);
    fill2<<<eb, TPB, 0, stream>>>(src, dst, ew, rowptr, pos, es, ew2, E);
    dinv_kernel<<<nb_thr, TPB, 0, stream>>>(rowptr, ew2, dinv, N);
    en_kernel<<<nb_waves, TPB, 0, stream>>>(rowptr, es, ew2, dinv, en, N);

    // lin0 + relu
    gemm64<true, true><<<(N + 3) / 4, TPB, 0, stream>>>(x, lin0_w, lin0_b, out, N);

    for (int i = 0; i < 2; ++i) {
        gemm64<false, false><<<(N + 3) / 4, TPB, 0, stream>>>(out, conv_w + (size_t)i * 64 * 64,
                                                              nullptr, h, N);
        gather_conv<<<nb_waves, TPB, 0, stream>>>(h, rowptr, es, en,
                                                  conv_b + (size_t)i * 64, out, N);
    }
}